// Round 1
// baseline (251.356 us; speedup 1.0000x reference)
//
#include <hip/hip_runtime.h>
#include <hip/hip_fp16.h>

#define HDIM 256
#define MS 16
#define LDAK 264   // 256 + 8 halves pad; measured-balanced for b128 reads & b64 writes
#define CSTRIDE (MS * LDAK * 2)   // 8448 B per channel block

typedef _Float16 half8 __attribute__((ext_vector_type(8)));
typedef _Float16 half4 __attribute__((ext_vector_type(4)));
typedef _Float16 half2v __attribute__((ext_vector_type(2)));
typedef float f32x4 __attribute__((ext_vector_type(4)));

__device__ __forceinline__ float fast_tanh(float x) {
    // tanh(x) = 1 - 2/(e^{2x}+1); v_exp-based, graceful at +-inf
    float e = __expf(2.0f * x);
    return 1.0f - 2.0f * __builtin_amdgcn_rcpf(e + 1.0f);
}

__device__ __forceinline__ half4 cvt4(float a, float b, float c, float d) {
    half2v lo = __builtin_bit_cast(half2v, __builtin_amdgcn_cvt_pkrtz(a, b));
    half2v hi = __builtin_bit_cast(half2v, __builtin_amdgcn_cvt_pkrtz(c, d));
    half4 r; r[0] = lo[0]; r[1] = lo[1]; r[2] = hi[0]; r[3] = hi[1];
    return r;
}

// Workgroup barrier draining only LDS (lgkmcnt) — leaves in-flight global
// wf prefetches (vmcnt) pending across the barrier (AITER-style: never
// vmcnt(0) at a barrier). LDS writes before the barrier are visible after.
__device__ __forceinline__ void barrier_lds() {
    asm volatile("s_waitcnt lgkmcnt(0)\n\ts_barrier" ::: "memory");
}

// Pack W1,W2,W3 (fp32 [256][256]) into f16 frag layout Wp[g*8192 + frag], g = flat
// K-step l*8+s; within a step: kg-sub*2048 + n*8 + (k&7).
__global__ __launch_bounds__(256) void pack_weights(const float* __restrict__ W1,
                                                    const float* __restrict__ W2,
                                                    const float* __restrict__ W3,
                                                    _Float16* __restrict__ out) {
    int tid = blockIdx.x * 256 + threadIdx.x;  // 0..24575
    int l = tid >> 13;
    int idx = tid & 8191;   // kg*256 + n
    int kg = idx >> 8;      // k-group of 8
    int n = idx & 255;
    const float* W = (l == 0) ? W1 : (l == 1) ? W2 : W3;
    half8 v;
    #pragma unroll
    for (int j = 0; j < 8; ++j) v[j] = (_Float16)W[(kg * 8 + j) * 256 + n];
    *(half8*)(out + l * 65536 + kg * 2048 + n * 8) = v;
}

__global__ __launch_bounds__(256, 2)
void pinn_fused(const float* __restrict__ x,
                const float* __restrict__ W0,
                const float* __restrict__ b0,
                const float* __restrict__ b1,
                const float* __restrict__ b2,
                const float* __restrict__ b3,
                const float* __restrict__ Wout,
                const float* __restrict__ bout,
                const _Float16* __restrict__ Wp,
                float* __restrict__ out) {
    // A: stacked [7 channels x 16 samples] rows x 256 k, f16, pad-264
    __shared__ __align__(16) _Float16 Abuf[7 * MS][LDAK];
    __shared__ float part[4 * 7 * MS];   // per-wave output partials (1792 B)

    const int tid  = threadIdx.x;
    const int lane = tid & 63;
    const int wid  = tid >> 6;        // wave 0..3 -> n-strip base wid*64
    const int qd   = lane >> 4;
    const int n15  = lane & 15;
    const int base = blockIdx.x * MS;
    const int nw   = wid * 64 + n15;

    // Linear W addressing: frag(g,t) at Wp + g*8192 + voff0 + t*128 (halves).
    const int voff0 = (qd * 256 + nw) * 8;

    const char* Ab = (const char*)Abuf;
    const int abase = (n15 * LDAK + qd * 8) * 2;                 // read base (bytes)
    char* Sb = (char*)Abuf;
    const int sbase = (n15 * LDAK + wid * 64 + qd * 4) * 2;      // write base (bytes)

    // K-step order per layer: EVEN s first {0,2,4,6}, then ODD {1,3,5,7}.
    // elem(t=0,1) of a layer writes cols [wid*64, wid*64+32) whose union over
    // waves == even-step k-ranges; t=2,3 == odd-step ranges. This lets each
    // layer's t23-elem VALU run in the same instruction stream as the next
    // layer's even K-step MFMAs with provably disjoint LDS regions.
    const int perm[8] = {0, 2, 4, 6, 1, 3, 5, 7};

    half8 wf[3][4];   // 3-deep rolling W pipeline over ordered step j

#define PREF(J) do { \
    if ((J) < 24) { \
        const int gp_ = (((J) >> 3) * 8) + perm[(J) & 7]; \
        _Pragma("unroll") \
        for (int t_ = 0; t_ < 4; ++t_) \
            wf[(J) % 3][t_] = *(const half8*)(Wp + gp_ * 8192 + voff0 + t_ * 128); \
    } \
} while (0)

#define KSTEP(ACC, J) do { \
    const int s_ = perm[(J) & 7]; \
    PREF((J) + 2); \
    half8 af_[7]; \
    _Pragma("unroll") \
    for (int c_ = 0; c_ < 7; ++c_) \
        af_[c_] = *(const half8*)(Ab + abase + c_ * CSTRIDE + s_ * 64); \
    _Pragma("unroll") \
    for (int c_ = 0; c_ < 7; ++c_) \
        _Pragma("unroll") \
        for (int t_ = 0; t_ < 4; ++t_) \
            ACC[c_][t_] = __builtin_amdgcn_mfma_f32_16x16x32_f16(wf[(J) % 3][t_], af_[c_], ACC[c_][t_], 0, 0, 0); \
} while (0)

// lane holds Z[m = n15][n = wid*64 + T*16 + qd*4 + r], r=0..3
#define ELEMW(ACC, BB, T) do { \
    const int ncol_ = wid * 64 + (T) * 16 + qd * 4; \
    f32x4 bv_ = *(const f32x4*)((BB) + ncol_); \
    float tv_[4], gj_[3][4], sj_[3][4]; \
    _Pragma("unroll") \
    for (int r_ = 0; r_ < 4; ++r_) { \
        float zv_ = ACC[0][T][r_] + bv_[r_]; \
        tv_[r_] = fast_tanh(zv_); \
        float dd_ = 1.f - tv_[r_] * tv_[r_]; \
        float c2_ = -2.f * tv_[r_] * dd_; \
        _Pragma("unroll") \
        for (int i_ = 0; i_ < 3; ++i_) { \
            float zg_ = ACC[1 + i_][T][r_]; \
            float zs_ = ACC[4 + i_][T][r_]; \
            gj_[i_][r_] = dd_ * zg_; \
            sj_[i_][r_] = dd_ * zs_ + c2_ * zg_ * zg_; \
        } \
    } \
    *(half4*)(Sb + sbase + 0 * CSTRIDE + (T) * 32) = cvt4(tv_[0], tv_[1], tv_[2], tv_[3]); \
    _Pragma("unroll") \
    for (int i_ = 0; i_ < 3; ++i_) { \
        *(half4*)(Sb + sbase + (1 + i_) * CSTRIDE + (T) * 32) = \
            cvt4(gj_[i_][0], gj_[i_][1], gj_[i_][2], gj_[i_][3]); \
        *(half4*)(Sb + sbase + (4 + i_) * CSTRIDE + (T) * 32) = \
            cvt4(sj_[i_][0], sj_[i_][1], sj_[i_][2], sj_[i_][3]); \
    } \
} while (0)

// layer 0 analytic jets for 8 consecutive cols at N0 (all 7 channels)
#define L0CHUNK(N0) do { \
    const int n0_ = (N0); \
    f32x4 w0v_[2], w1v_[2], w2v_[2], b0v_[2]; \
    w0v_[0] = *(const f32x4*)(W0 + n0_);            w0v_[1] = *(const f32x4*)(W0 + n0_ + 4); \
    w1v_[0] = *(const f32x4*)(W0 + HDIM + n0_);     w1v_[1] = *(const f32x4*)(W0 + HDIM + n0_ + 4); \
    w2v_[0] = *(const f32x4*)(W0 + 2 * HDIM + n0_); w2v_[1] = *(const f32x4*)(W0 + 2 * HDIM + n0_ + 4); \
    b0v_[0] = *(const f32x4*)(b0 + n0_);            b0v_[1] = *(const f32x4*)(b0 + n0_ + 4); \
    half8 h_[7]; \
    _Pragma("unroll") \
    for (int r_ = 0; r_ < 8; ++r_) { \
        const float w0_ = w0v_[r_ >> 2][r_ & 3]; \
        const float w1_ = w1v_[r_ >> 2][r_ & 3]; \
        const float w2_ = w2v_[r_ >> 2][r_ & 3]; \
        float z_  = x0 * w0_ + x1 * w1_ + x2 * w2_ + b0v_[r_ >> 2][r_ & 3]; \
        float tv_ = fast_tanh(z_); \
        float dd_ = 1.f - tv_ * tv_; \
        float c2_ = -2.f * tv_ * dd_; \
        h_[0][r_] = (_Float16)tv_; \
        h_[1][r_] = (_Float16)(dd_ * w0_); \
        h_[2][r_] = (_Float16)(dd_ * w1_); \
        h_[3][r_] = (_Float16)(dd_ * w2_); \
        h_[4][r_] = (_Float16)(c2_ * w0_ * w0_); \
        h_[5][r_] = (_Float16)(c2_ * w1_ * w1_); \
        h_[6][r_] = (_Float16)(c2_ * w2_ * w2_); \
    } \
    _Pragma("unroll") \
    for (int c_ = 0; c_ < 7; ++c_) \
        *(half8*)&Abuf[c_ * MS + m0][n0_] = h_[c_]; \
} while (0)

    // initial W prefetch: ordered steps 0 (g=0) and 1 (g=2)
    PREF(0);
    PREF(1);

    // ---------------- layer 0: 3 -> 256, jets analytic; even/odd col split ----------------
    const int m0 = tid & 15;
    const int cidx = tid >> 4;                        // 0..15
    const int n0A = (cidx >> 2) * 64 + (cidx & 3) * 8; // even-region chunk
    const float x0 = x[(base + m0) * 3 + 0];
    const float x1 = x[(base + m0) * 3 + 1];
    const float x2 = x[(base + m0) * 3 + 2];

    L0CHUNK(n0A);          // even-region cols [q*64, q*64+32)
    barrier_lds();

    // ---------------- layer 1 ----------------
    f32x4 acc1[7][4];
    #pragma unroll
    for (int c = 0; c < 7; ++c)
        #pragma unroll
        for (int t = 0; t < 4; ++t) acc1[c][t] = (f32x4){0.f, 0.f, 0.f, 0.f};

    // K1-even (reads even region) interleaved with L0 odd-chunk (writes odd region)
    KSTEP(acc1, 0);
    L0CHUNK(n0A + 32);     // odd-region cols; disjoint from even-step reads
    KSTEP(acc1, 1);
    KSTEP(acc1, 2);
    KSTEP(acc1, 3);
    barrier_lds();
    KSTEP(acc1, 4); KSTEP(acc1, 5); KSTEP(acc1, 6); KSTEP(acc1, 7);
    // odd steps read odd region only -> safe to write even region now
    ELEMW(acc1, b1, 0);
    ELEMW(acc1, b1, 1);
    barrier_lds();

    // ---------------- layer 2 ----------------
    f32x4 acc2[7][4];
    #pragma unroll
    for (int c = 0; c < 7; ++c)
        #pragma unroll
        for (int t = 0; t < 4; ++t) acc2[c][t] = (f32x4){0.f, 0.f, 0.f, 0.f};

    // K2-even (reads even region) interleaved with elem1 t2/t3 (writes odd region)
    KSTEP(acc2, 8);
    ELEMW(acc1, b1, 2);
    KSTEP(acc2, 9);
    KSTEP(acc2, 10);
    ELEMW(acc1, b1, 3);
    KSTEP(acc2, 11);
    barrier_lds();
    KSTEP(acc2, 12); KSTEP(acc2, 13); KSTEP(acc2, 14); KSTEP(acc2, 15);
    ELEMW(acc2, b2, 0);
    ELEMW(acc2, b2, 1);
    barrier_lds();

    // ---------------- layer 3: K-loop + FUSED elem/output ----------------
    f32x4 acc3[7][4];
    #pragma unroll
    for (int c = 0; c < 7; ++c)
        #pragma unroll
        for (int t = 0; t < 4; ++t) acc3[c][t] = (f32x4){0.f, 0.f, 0.f, 0.f};

    // K3-even interleaved with elem2 t2/t3
    KSTEP(acc3, 16);
    ELEMW(acc2, b2, 2);
    KSTEP(acc3, 17);
    KSTEP(acc3, 18);
    ELEMW(acc2, b2, 3);
    KSTEP(acc3, 19);
    barrier_lds();
    KSTEP(acc3, 20); KSTEP(acc3, 21); KSTEP(acc3, 22); KSTEP(acc3, 23);
    // No post-K barrier: fused elem touches only registers + `part`.

    {
        // per-lane partial dot with Wout over this lane's 16 columns (fp32 path)
        float p[7] = {0.f, 0.f, 0.f, 0.f, 0.f, 0.f, 0.f};
        #pragma unroll
        for (int t = 0; t < 4; ++t) {
            const int ncol = wid * 64 + t * 16 + qd * 4;
            f32x4 bv = *(const f32x4*)(b3 + ncol);
            f32x4 wv = *(const f32x4*)(Wout + ncol);
            #pragma unroll
            for (int r = 0; r < 4; ++r) {
                float zv = acc3[0][t][r] + bv[r];
                float tv = fast_tanh(zv);
                float dd = 1.f - tv * tv;
                float c2 = -2.f * tv * dd;
                p[0] += tv * wv[r];
                #pragma unroll
                for (int i = 0; i < 3; ++i) {
                    float zg = acc3[1 + i][t][r];
                    float zs = acc3[4 + i][t][r];
                    p[1 + i] += (dd * zg) * wv[r];
                    p[4 + i] += (dd * zs + c2 * zg * zg) * wv[r];
                }
            }
        }
        // reduce over the 4 qd lanes sharing sample n15
        #pragma unroll
        for (int c = 0; c < 7; ++c) {
            p[c] += __shfl_xor(p[c], 16, 64);
            p[c] += __shfl_xor(p[c], 32, 64);
        }
        if (lane < 16) {
            #pragma unroll
            for (int c = 0; c < 7; ++c)
                part[(wid * 7 + c) * MS + lane] = p[c];
        }
    }
    barrier_lds();

    // ---------------- final reduce across the 4 waves; store [B,7] ----------------
    if (tid < 7 * MS) {
        const int c = tid >> 4;   // channel
        const int m = tid & 15;   // sample
        float v = part[(0 * 7 + c) * MS + m] + part[(1 * 7 + c) * MS + m] +
                  part[(2 * 7 + c) * MS + m] + part[(3 * 7 + c) * MS + m];
        if (c == 0) v += bout[0];
        out[(base + m) * 7 + c] = v;
    }

#undef PREF
#undef KSTEP
#undef ELEMW
#undef L0CHUNK
}

extern "C" void kernel_launch(void* const* d_in, const int* in_sizes, int n_in,
                              void* d_out, int out_size, void* d_ws, size_t ws_size,
                              hipStream_t stream) {
    const float* xp   = (const float*)d_in[0];
    const float* W0   = (const float*)d_in[1];
    const float* b0   = (const float*)d_in[2];
    const float* W1   = (const float*)d_in[3];
    const float* b1   = (const float*)d_in[4];
    const float* W2   = (const float*)d_in[5];
    const float* b2   = (const float*)d_in[6];
    const float* W3   = (const float*)d_in[7];
    const float* b3   = (const float*)d_in[8];
    const float* Wout = (const float*)d_in[9];
    const float* bout = (const float*)d_in[10];
    _Float16* Wp = (_Float16*)d_ws;  // 3 * 65536 halves = 384 KB

    pack_weights<<<96, 256, 0, stream>>>(W1, W2, W3, Wp);
    pinn_fused<<<65536 / MS, 256, 0, stream>>>(xp, W0, b0, b1, b2, b3, Wout, bout, Wp,
                                               (float*)d_out);
}